// Round 2
// baseline (16574.847 us; speedup 1.0000x reference)
//
#include <hip/hip_runtime.h>
#include <math.h>

// ---------------------------------------------------------------------------
// All intermediates live in static __device__ arrays: no d_ws usage at all
// (round-1 failure suspect: 64MiB ws footprint with stats at the 64MiB edge).
// Entire pipeline in f64 to track the numpy-f64 reference to ~1e-13.
// ---------------------------------------------------------------------------

#define NELEM (16 * 64 * 64 * 64)  // 4194304, B*C*H*W with C=64

__device__ double g_y1[NELEM];    // conv1 out (f64) -> overwritten in-place by spike1
__device__ double g_ysc[NELEM];   // 1x1 shortcut conv out (f64)
__device__ double g_y2[NELEM];    // conv2 out (f64)
__device__ double g_part[384][1024];  // per-block stat partials
__device__ double g_stats[384];       // reduced sums: [0..63]=s1 [64..127]=q1
                                      // [128..191]=ssc [192..255]=qsc
                                      // [256..319]=s2 [320..383]=q2
__device__ double g_prm[384];     // [0]=bn1 scale,[64]=bn1 shift,[128]=sc scale,
                                  // [192]=sc shift,[256]=bn2 scale,[320]=bn2 shift
__device__ double g_w1d[64 * 32 * 9];
__device__ double g_b1d[64];
__device__ double g_scwd[64 * 32];
__device__ double g_w2d[64 * 64 * 9];

// ---------------- weight upconvert (f32 -> f64, exact) ----------------------
__global__ void prep_kernel(const float* __restrict__ w1, const float* __restrict__ b1,
                            const float* __restrict__ scw, const float* __restrict__ w2)
{
  int i = blockIdx.x * 256 + threadIdx.x;
  if (i < 64 * 32 * 9) g_w1d[i] = (double)w1[i];
  if (i < 64)          g_b1d[i] = (double)b1[i];
  if (i < 64 * 32)     g_scwd[i] = (double)scw[i];
  if (i < 64 * 64 * 9) g_w2d[i] = (double)w2[i];
}

__device__ __forceinline__ double wave_sum64(double v) {
#pragma unroll
  for (int m = 1; m < 64; m <<= 1) v += __shfl_xor(v, m);
  return v;
}

// ---------------- conv1 (3x3, 32->64, bias) + sc conv (1x1) -----------------
__global__ __launch_bounds__(256) void conv1_sc_kernel(const float* __restrict__ x)
{
  const int b = blockIdx.x >> 6, h = blockIdx.x & 63;
  const int w = threadIdx.x & 63;
  const int cog = __builtin_amdgcn_readfirstlane(threadIdx.x >> 6);  // 0..3
  __shared__ float xs[3][32][64];
  for (int i = threadIdx.x; i < 3 * 32 * 64; i += 256) {
    int kh = i >> 11, ci = (i >> 6) & 31, ww = i & 63;
    int hh = h + kh - 1;
    xs[kh][ci][ww] = ((unsigned)hh < 64u) ? x[((b * 32 + ci) << 12) + (hh << 6) + ww] : 0.f;
  }
  __syncthreads();

  double acc[16], asc[16];
#pragma unroll
  for (int i = 0; i < 16; ++i) { acc[i] = g_b1d[cog * 16 + i]; asc[i] = 0.0; }

  for (int ci = 0; ci < 32; ++ci) {
    double xv[3][3];
#pragma unroll
    for (int kh = 0; kh < 3; ++kh) {
      xv[kh][0] = (w > 0)  ? (double)xs[kh][ci][w - 1] : 0.0;
      xv[kh][1] = (double)xs[kh][ci][w];
      xv[kh][2] = (w < 63) ? (double)xs[kh][ci][w + 1] : 0.0;
    }
#pragma unroll
    for (int i = 0; i < 16; ++i) {
      const int co = cog * 16 + i;
      const double* wp = &g_w1d[(co * 32 + ci) * 9];
      double a = acc[i];
#pragma unroll
      for (int k = 0; k < 9; ++k) a = fma(xv[k / 3][k % 3], wp[k], a);
      acc[i] = a;
      asc[i] = fma(xv[1][1], g_scwd[co * 32 + ci], asc[i]);
    }
  }

#pragma unroll
  for (int i = 0; i < 16; ++i) {
    const int co = cog * 16 + i;
    const int oidx = ((b * 64 + co) << 12) + (h << 6) + w;
    double v = acc[i], u = asc[i];
    g_y1[oidx] = v;
    g_ysc[oidx] = u;
    double s = wave_sum64(v), q = wave_sum64(v * v);
    double ss = wave_sum64(u), qq = wave_sum64(u * u);
    if (w == 0) {
      g_part[co][blockIdx.x] = s;        g_part[64 + co][blockIdx.x] = q;
      g_part[128 + co][blockIdx.x] = ss; g_part[192 + co][blockIdx.x] = qq;
    }
  }
}

// ---------------- conv2 (3x3, 64->64, no bias) ------------------------------
__global__ __launch_bounds__(256) void conv2_kernel()
{
  const int b = blockIdx.x >> 6, h = blockIdx.x & 63;
  const int w = threadIdx.x & 63;
  const int cog = __builtin_amdgcn_readfirstlane(threadIdx.x >> 6);
  __shared__ float xs[3][64][64];   // spike values {0,1}: f32 exact
  for (int i = threadIdx.x; i < 3 * 64 * 64; i += 256) {
    int kh = i >> 12, ci = (i >> 6) & 63, ww = i & 63;
    int hh = h + kh - 1;
    xs[kh][ci][ww] = ((unsigned)hh < 64u) ? (float)g_y1[((b * 64 + ci) << 12) + (hh << 6) + ww] : 0.f;
  }
  __syncthreads();

  double acc[16];
#pragma unroll
  for (int i = 0; i < 16; ++i) acc[i] = 0.0;

  for (int ci = 0; ci < 64; ++ci) {
    double xv[3][3];
#pragma unroll
    for (int kh = 0; kh < 3; ++kh) {
      xv[kh][0] = (w > 0)  ? (double)xs[kh][ci][w - 1] : 0.0;
      xv[kh][1] = (double)xs[kh][ci][w];
      xv[kh][2] = (w < 63) ? (double)xs[kh][ci][w + 1] : 0.0;
    }
#pragma unroll
    for (int i = 0; i < 16; ++i) {
      const int co = cog * 16 + i;
      const double* wp = &g_w2d[(co * 64 + ci) * 9];
      double a = acc[i];
#pragma unroll
      for (int k = 0; k < 9; ++k) a = fma(xv[k / 3][k % 3], wp[k], a);
      acc[i] = a;
    }
  }

#pragma unroll
  for (int i = 0; i < 16; ++i) {
    const int co = cog * 16 + i;
    double v = acc[i];
    g_y2[((b * 64 + co) << 12) + (h << 6) + w] = v;
    double s = wave_sum64(v), q = wave_sum64(v * v);
    if (w == 0) { g_part[256 + co][blockIdx.x] = s; g_part[320 + co][blockIdx.x] = q; }
  }
}

// ---------------- deterministic stat reduction ------------------------------
__global__ __launch_bounds__(256) void reduce_stats(int base)
{
  const int row = base + blockIdx.x;
  const int t = threadIdx.x;
  double s = g_part[row][t] + g_part[row][t + 256] + g_part[row][t + 512] + g_part[row][t + 768];
  s = wave_sum64(s);
  __shared__ double ls[4];
  if ((t & 63) == 0) ls[t >> 6] = s;
  __syncthreads();
  if (t == 0) g_stats[row] = ls[0] + ls[1] + ls[2] + ls[3];
}

// ---------------- BN params: scale = g*rstd, shift = b - m*scale ------------
__global__ void bn_params(int s_off, int q_off, int p_off,
                          const float* __restrict__ g, const float* __restrict__ bta)
{
  int c = threadIdx.x;
  const double inv = 1.0 / 65536.0;
  double m = g_stats[s_off + c] * inv;
  double v = g_stats[q_off + c] * inv - m * m;
  double rstd = 1.0 / sqrt(v + 1e-5);
  double sc = (double)g[c] * rstd;
  g_prm[p_off + c] = sc;
  g_prm[p_off + 64 + c] = (double)bta[c] - m * sc;
}

// ---------------- ODE (dopri5, 5 steps, f64) + spike [+ residual] -----------
__device__ __forceinline__ double bcast_d(double v, int l) {
  union { double d; unsigned u[2]; } a;
  a.d = v;
  a.u[0] = __builtin_amdgcn_readlane(a.u[0], l);
  a.u[1] = __builtin_amdgcn_readlane(a.u[1], l);
  return a.d;
}

template <bool RES>
__global__ __launch_bounds__(256, 2) void ode_kernel(
    int prm_off, const float* __restrict__ wodep, const float* __restrict__ wtgp,
    const float* __restrict__ tgbp, double thr, float* __restrict__ outf)
{
  const int lane = threadIdx.x & 63;
  const int wv = __builtin_amdgcn_readfirstlane(threadIdx.x >> 6);
  float wo[64], wt[64];
#pragma unroll
  for (int i = 0; i < 64; ++i) wo[i] = wodep[(i << 6) + lane];   // w_ode[i][lane]
#pragma unroll
  for (int i = 0; i < 64; ++i) wt[i] = wtgp[(lane << 6) + i];    // tg_w[lane][i]
  const double tb = (double)tgbp[lane];

  auto feval = [&](double xsv) -> double {
    double ao0 = 0.0, ao1 = 0.0, at0 = 0.0, at1 = 0.0;
#pragma unroll
    for (int i = 0; i < 64; i += 2) {
      double xa = bcast_d(xsv, i);
      double xb = bcast_d(xsv, i + 1);
      ao0 = fma(xa, (double)wo[i], ao0);
      at0 = fma(xa, (double)wt[i], at0);
      ao1 = fma(xb, (double)wo[i + 1], ao1);
      at1 = fma(xb, (double)wt[i + 1], at1);
    }
    double ao = ao0 + ao1;
    double z = (at0 + at1) + tb;
    double g = 0.5 * ao * (1.0 + erf(ao * 0.70710678118654752440));
    double s = 1.0 / (1.0 + exp(-z));       // sigmoid
    double tf = 1.0 / (1.0 + s);
    return g * tf;
  };

  const double H = 1.0 / 5.0;
  const double A21 = 1.0 / 5.0;
  const double A31 = 3.0 / 40.0, A32 = 9.0 / 40.0;
  const double A41 = 44.0 / 45.0, A42 = -56.0 / 15.0, A43 = 32.0 / 9.0;
  const double A51 = 19372.0 / 6561.0, A52 = -25360.0 / 2187.0,
               A53 = 64448.0 / 6561.0, A54 = -212.0 / 729.0;
  const double A61 = 9017.0 / 3168.0, A62 = -355.0 / 33.0,
               A63 = 46732.0 / 5247.0, A64 = 49.0 / 176.0, A65 = -5103.0 / 18656.0;
  const double B1 = 35.0 / 384.0, B3 = 500.0 / 1113.0, B4 = 125.0 / 192.0,
               B5 = -2187.0 / 6784.0, B6 = 11.0 / 84.0;

  const int base = (blockIdx.x * 4 + wv) * 2;
#pragma unroll 1
  for (int r = 0; r < 2; ++r) {
    const int row = base + r;
    const int c = (row >> 6) & 63;
    const int idx = (row << 6) + lane;
    const double psc = g_prm[prm_off + c], psh = g_prm[prm_off + 64 + c];
    double xv = fma(RES ? g_y2[idx] : g_y1[idx], psc, psh);

#pragma unroll 1
    for (int st5 = 0; st5 < 5; ++st5) {
      double k1 = feval(xv);
      double k2 = feval(xv + H * (A21 * k1));
      double k3 = feval(xv + H * (A31 * k1 + A32 * k2));
      double k4 = feval(xv + H * (A41 * k1 + A42 * k2 + A43 * k3));
      double k5 = feval(xv + H * (A51 * k1 + A52 * k2 + A53 * k3 + A54 * k4));
      double k6 = feval(xv + H * (A61 * k1 + A62 * k2 + A63 * k3 + A64 * k4 + A65 * k5));
      xv = xv + H * (B1 * k1 + B3 * k3 + B4 * k4 + B5 * k5 + B6 * k6);
    }

    double o = (xv - thr > 0.0) ? 1.0 : 0.0;
    if (RES) {
      double res = fma(g_ysc[idx], g_prm[128 + c], g_prm[192 + c]);
      outf[idx] = (float)(o + res);
    } else {
      g_y1[idx] = o;   // in-place spike, exact {0,1}
    }
  }
}

// ---------------- launch ----------------------------------------------------
extern "C" void kernel_launch(void* const* d_in, const int* in_sizes, int n_in,
                              void* d_out, int out_size, void* d_ws, size_t ws_size,
                              hipStream_t stream)
{
  const float* x    = (const float*)d_in[0];
  const float* c1w  = (const float*)d_in[1];
  const float* c1b  = (const float*)d_in[2];
  const float* bn1g = (const float*)d_in[3];
  const float* bn1b = (const float*)d_in[4];
  const float* o1w  = (const float*)d_in[5];
  const float* t1w  = (const float*)d_in[6];
  const float* t1b  = (const float*)d_in[7];
  const float* c2w  = (const float*)d_in[8];
  const float* bn2g = (const float*)d_in[9];
  const float* bn2b = (const float*)d_in[10];
  const float* o2w  = (const float*)d_in[11];
  const float* t2w  = (const float*)d_in[12];
  const float* t2b  = (const float*)d_in[13];
  const float* scw  = (const float*)d_in[14];
  const float* scg  = (const float*)d_in[15];
  const float* scb  = (const float*)d_in[16];

  prep_kernel<<<144, 256, 0, stream>>>(c1w, c1b, scw, c2w);

  conv1_sc_kernel<<<1024, 256, 0, stream>>>(x);
  reduce_stats<<<256, 256, 0, stream>>>(0);
  bn_params<<<1, 64, 0, stream>>>(0, 64, 0, bn1g, bn1b);
  bn_params<<<1, 64, 0, stream>>>(128, 192, 128, scg, scb);

  ode_kernel<false><<<8192, 256, 0, stream>>>(0, o1w, t1w, t1b, 0.3, nullptr);

  conv2_kernel<<<1024, 256, 0, stream>>>();
  reduce_stats<<<128, 256, 0, stream>>>(256);
  bn_params<<<1, 64, 0, stream>>>(256, 320, 256, bn2g, bn2b);

  ode_kernel<true><<<8192, 256, 0, stream>>>(256, o2w, t2w, t2b, 0.5, (float*)d_out);
}

// Round 3
// 5063.822 us; speedup vs baseline: 3.2732x; 3.2732x over previous
//
#include <hip/hip_runtime.h>
#include <math.h>

// ---------------------------------------------------------------------------
// R3: same f64 pipeline as R2 (which passed), but the ODE kernel keeps the
// weight matrices in LDS (f32, exact) instead of 128 per-lane VGPRs.
// R2's ODE was spill-bound: FETCH 5.2GB/dispatch vs 35MB true footprint.
// ---------------------------------------------------------------------------

#define NELEM (16 * 64 * 64 * 64)  // 4194304, B*C*H*W with C=64

__device__ double g_y1[NELEM];    // conv1 out (f64) -> overwritten in-place by spike1
__device__ double g_ysc[NELEM];   // 1x1 shortcut conv out (f64)
__device__ double g_y2[NELEM];    // conv2 out (f64)
__device__ double g_part[384][1024];  // per-block stat partials
__device__ double g_stats[384];
__device__ double g_prm[384];     // [0]=bn1 sc,[64]=bn1 sh,[128]=sc sc,[192]=sc sh,
                                  // [256]=bn2 sc,[320]=bn2 sh
__device__ double g_w1d[64 * 32 * 9];
__device__ double g_b1d[64];
__device__ double g_scwd[64 * 32];
__device__ double g_w2d[64 * 64 * 9];

// ---------------- weight upconvert (f32 -> f64, exact) ----------------------
__global__ void prep_kernel(const float* __restrict__ w1, const float* __restrict__ b1,
                            const float* __restrict__ scw, const float* __restrict__ w2)
{
  int i = blockIdx.x * 256 + threadIdx.x;
  if (i < 64 * 32 * 9) g_w1d[i] = (double)w1[i];
  if (i < 64)          g_b1d[i] = (double)b1[i];
  if (i < 64 * 32)     g_scwd[i] = (double)scw[i];
  if (i < 64 * 64 * 9) g_w2d[i] = (double)w2[i];
}

__device__ __forceinline__ double wave_sum64(double v) {
#pragma unroll
  for (int m = 1; m < 64; m <<= 1) v += __shfl_xor(v, m);
  return v;
}

// ---------------- conv1 (3x3, 32->64, bias) + sc conv (1x1) -----------------
__global__ __launch_bounds__(256) void conv1_sc_kernel(const float* __restrict__ x)
{
  const int b = blockIdx.x >> 6, h = blockIdx.x & 63;
  const int w = threadIdx.x & 63;
  const int cog = __builtin_amdgcn_readfirstlane(threadIdx.x >> 6);  // 0..3
  __shared__ float xs[3][32][64];
  for (int i = threadIdx.x; i < 3 * 32 * 64; i += 256) {
    int kh = i >> 11, ci = (i >> 6) & 31, ww = i & 63;
    int hh = h + kh - 1;
    xs[kh][ci][ww] = ((unsigned)hh < 64u) ? x[((b * 32 + ci) << 12) + (hh << 6) + ww] : 0.f;
  }
  __syncthreads();

  double acc[16], asc[16];
#pragma unroll
  for (int i = 0; i < 16; ++i) { acc[i] = g_b1d[cog * 16 + i]; asc[i] = 0.0; }

  for (int ci = 0; ci < 32; ++ci) {
    double xv[3][3];
#pragma unroll
    for (int kh = 0; kh < 3; ++kh) {
      xv[kh][0] = (w > 0)  ? (double)xs[kh][ci][w - 1] : 0.0;
      xv[kh][1] = (double)xs[kh][ci][w];
      xv[kh][2] = (w < 63) ? (double)xs[kh][ci][w + 1] : 0.0;
    }
#pragma unroll
    for (int i = 0; i < 16; ++i) {
      const int co = cog * 16 + i;
      const double* wp = &g_w1d[(co * 32 + ci) * 9];
      double a = acc[i];
#pragma unroll
      for (int k = 0; k < 9; ++k) a = fma(xv[k / 3][k % 3], wp[k], a);
      acc[i] = a;
      asc[i] = fma(xv[1][1], g_scwd[co * 32 + ci], asc[i]);
    }
  }

#pragma unroll
  for (int i = 0; i < 16; ++i) {
    const int co = cog * 16 + i;
    const int oidx = ((b * 64 + co) << 12) + (h << 6) + w;
    double v = acc[i], u = asc[i];
    g_y1[oidx] = v;
    g_ysc[oidx] = u;
    double s = wave_sum64(v), q = wave_sum64(v * v);
    double ss = wave_sum64(u), qq = wave_sum64(u * u);
    if (w == 0) {
      g_part[co][blockIdx.x] = s;        g_part[64 + co][blockIdx.x] = q;
      g_part[128 + co][blockIdx.x] = ss; g_part[192 + co][blockIdx.x] = qq;
    }
  }
}

// ---------------- conv2 (3x3, 64->64, no bias) ------------------------------
__global__ __launch_bounds__(256) void conv2_kernel()
{
  const int b = blockIdx.x >> 6, h = blockIdx.x & 63;
  const int w = threadIdx.x & 63;
  const int cog = __builtin_amdgcn_readfirstlane(threadIdx.x >> 6);
  __shared__ float xs[3][64][64];   // spike values {0,1}: f32 exact
  for (int i = threadIdx.x; i < 3 * 64 * 64; i += 256) {
    int kh = i >> 12, ci = (i >> 6) & 63, ww = i & 63;
    int hh = h + kh - 1;
    xs[kh][ci][ww] = ((unsigned)hh < 64u) ? (float)g_y1[((b * 64 + ci) << 12) + (hh << 6) + ww] : 0.f;
  }
  __syncthreads();

  double acc[16];
#pragma unroll
  for (int i = 0; i < 16; ++i) acc[i] = 0.0;

  for (int ci = 0; ci < 64; ++ci) {
    double xv[3][3];
#pragma unroll
    for (int kh = 0; kh < 3; ++kh) {
      xv[kh][0] = (w > 0)  ? (double)xs[kh][ci][w - 1] : 0.0;
      xv[kh][1] = (double)xs[kh][ci][w];
      xv[kh][2] = (w < 63) ? (double)xs[kh][ci][w + 1] : 0.0;
    }
#pragma unroll
    for (int i = 0; i < 16; ++i) {
      const int co = cog * 16 + i;
      const double* wp = &g_w2d[(co * 64 + ci) * 9];
      double a = acc[i];
#pragma unroll
      for (int k = 0; k < 9; ++k) a = fma(xv[k / 3][k % 3], wp[k], a);
      acc[i] = a;
    }
  }

#pragma unroll
  for (int i = 0; i < 16; ++i) {
    const int co = cog * 16 + i;
    double v = acc[i];
    g_y2[((b * 64 + co) << 12) + (h << 6) + w] = v;
    double s = wave_sum64(v), q = wave_sum64(v * v);
    if (w == 0) { g_part[256 + co][blockIdx.x] = s; g_part[320 + co][blockIdx.x] = q; }
  }
}

// ---------------- deterministic stat reduction ------------------------------
__global__ __launch_bounds__(256) void reduce_stats(int base)
{
  const int row = base + blockIdx.x;
  const int t = threadIdx.x;
  double s = g_part[row][t] + g_part[row][t + 256] + g_part[row][t + 512] + g_part[row][t + 768];
  s = wave_sum64(s);
  __shared__ double ls[4];
  if ((t & 63) == 0) ls[t >> 6] = s;
  __syncthreads();
  if (t == 0) g_stats[row] = ls[0] + ls[1] + ls[2] + ls[3];
}

// ---------------- BN params: scale = g*rstd, shift = b - m*scale ------------
__global__ void bn_params(int s_off, int q_off, int p_off,
                          const float* __restrict__ g, const float* __restrict__ bta)
{
  int c = threadIdx.x;
  const double inv = 1.0 / 65536.0;
  double m = g_stats[s_off + c] * inv;
  double v = g_stats[q_off + c] * inv - m * m;
  double rstd = 1.0 / sqrt(v + 1e-5);
  double sc = (double)g[c] * rstd;
  g_prm[p_off + c] = sc;
  g_prm[p_off + 64 + c] = (double)bta[c] - m * sc;
}

// ---------------- ODE (dopri5, 5 steps, f64) + spike [+ residual] -----------
// Weights live in LDS as f32 (exact inputs), converted to f64 at use.
// wos: w_ode row-major (lane j reads column j -> conflict-free).
// wts: tg_w TRANSPOSED (wts[i*64+j] = tg_w[j][i]) -> conflict-free.
__device__ __forceinline__ double bcast_d(double v, int l) {
  union { double d; unsigned u[2]; } a;
  a.d = v;
  a.u[0] = __builtin_amdgcn_readlane(a.u[0], l);
  a.u[1] = __builtin_amdgcn_readlane(a.u[1], l);
  return a.d;
}

template <bool RES>
__global__ __launch_bounds__(256, 4) void ode_kernel(
    int prm_off, const float* __restrict__ wodep, const float* __restrict__ wtgp,
    const float* __restrict__ tgbp, double thr, float* __restrict__ outf)
{
  __shared__ float wos[64 * 64];
  __shared__ float wts[64 * 64];
  for (int t = threadIdx.x; t < 4096; t += 256) {
    wos[t] = wodep[t];
    int i = t >> 6, j = t & 63;
    wts[t] = wtgp[j * 64 + i];
  }
  __syncthreads();

  const int lane = threadIdx.x & 63;
  const int wv = __builtin_amdgcn_readfirstlane(threadIdx.x >> 6);
  const double tb = (double)tgbp[lane];

  auto feval = [&](double xsv) -> double {
    double ao0 = 0.0, ao1 = 0.0, ao2 = 0.0, ao3 = 0.0;
    double at0 = 0.0, at1 = 0.0, at2 = 0.0, at3 = 0.0;
#pragma unroll
    for (int i = 0; i < 64; i += 4) {
      double x0 = bcast_d(xsv, i);
      double x1 = bcast_d(xsv, i + 1);
      double x2 = bcast_d(xsv, i + 2);
      double x3 = bcast_d(xsv, i + 3);
      ao0 = fma(x0, (double)wos[(i + 0) * 64 + lane], ao0);
      at0 = fma(x0, (double)wts[(i + 0) * 64 + lane], at0);
      ao1 = fma(x1, (double)wos[(i + 1) * 64 + lane], ao1);
      at1 = fma(x1, (double)wts[(i + 1) * 64 + lane], at1);
      ao2 = fma(x2, (double)wos[(i + 2) * 64 + lane], ao2);
      at2 = fma(x2, (double)wts[(i + 2) * 64 + lane], at2);
      ao3 = fma(x3, (double)wos[(i + 3) * 64 + lane], ao3);
      at3 = fma(x3, (double)wts[(i + 3) * 64 + lane], at3);
    }
    double ao = (ao0 + ao1) + (ao2 + ao3);
    double z = ((at0 + at1) + (at2 + at3)) + tb;
    double g = 0.5 * ao * (1.0 + erf(ao * 0.70710678118654752440));
    double s = 1.0 / (1.0 + exp(-z));       // sigmoid
    double tf = 1.0 / (1.0 + s);
    return g * tf;
  };

  const double H = 1.0 / 5.0;
  const double A21 = 1.0 / 5.0;
  const double A31 = 3.0 / 40.0, A32 = 9.0 / 40.0;
  const double A41 = 44.0 / 45.0, A42 = -56.0 / 15.0, A43 = 32.0 / 9.0;
  const double A51 = 19372.0 / 6561.0, A52 = -25360.0 / 2187.0,
               A53 = 64448.0 / 6561.0, A54 = -212.0 / 729.0;
  const double A61 = 9017.0 / 3168.0, A62 = -355.0 / 33.0,
               A63 = 46732.0 / 5247.0, A64 = 49.0 / 176.0, A65 = -5103.0 / 18656.0;
  const double B1 = 35.0 / 384.0, B3 = 500.0 / 1113.0, B4 = 125.0 / 192.0,
               B5 = -2187.0 / 6784.0, B6 = 11.0 / 84.0;

  const int row = blockIdx.x * 4 + wv;      // one row per wave
  const int c = (row >> 6) & 63;
  const int idx = (row << 6) + lane;
  const double psc = g_prm[prm_off + c], psh = g_prm[prm_off + 64 + c];
  double xv = fma(RES ? g_y2[idx] : g_y1[idx], psc, psh);

#pragma unroll 1
  for (int st5 = 0; st5 < 5; ++st5) {
    double k1 = feval(xv);
    double k2 = feval(xv + H * (A21 * k1));
    double k3 = feval(xv + H * (A31 * k1 + A32 * k2));
    double k4 = feval(xv + H * (A41 * k1 + A42 * k2 + A43 * k3));
    double k5 = feval(xv + H * (A51 * k1 + A52 * k2 + A53 * k3 + A54 * k4));
    double k6 = feval(xv + H * (A61 * k1 + A62 * k2 + A63 * k3 + A64 * k4 + A65 * k5));
    xv = xv + H * (B1 * k1 + B3 * k3 + B4 * k4 + B5 * k5 + B6 * k6);
  }

  double o = (xv - thr > 0.0) ? 1.0 : 0.0;
  if (RES) {
    double res = fma(g_ysc[idx], g_prm[128 + c], g_prm[192 + c]);
    outf[idx] = (float)(o + res);
  } else {
    g_y1[idx] = o;   // in-place spike, exact {0,1}
  }
}

// ---------------- launch ----------------------------------------------------
extern "C" void kernel_launch(void* const* d_in, const int* in_sizes, int n_in,
                              void* d_out, int out_size, void* d_ws, size_t ws_size,
                              hipStream_t stream)
{
  const float* x    = (const float*)d_in[0];
  const float* c1w  = (const float*)d_in[1];
  const float* c1b  = (const float*)d_in[2];
  const float* bn1g = (const float*)d_in[3];
  const float* bn1b = (const float*)d_in[4];
  const float* o1w  = (const float*)d_in[5];
  const float* t1w  = (const float*)d_in[6];
  const float* t1b  = (const float*)d_in[7];
  const float* c2w  = (const float*)d_in[8];
  const float* bn2g = (const float*)d_in[9];
  const float* bn2b = (const float*)d_in[10];
  const float* o2w  = (const float*)d_in[11];
  const float* t2w  = (const float*)d_in[12];
  const float* t2b  = (const float*)d_in[13];
  const float* scw  = (const float*)d_in[14];
  const float* scg  = (const float*)d_in[15];
  const float* scb  = (const float*)d_in[16];

  prep_kernel<<<144, 256, 0, stream>>>(c1w, c1b, scw, c2w);

  conv1_sc_kernel<<<1024, 256, 0, stream>>>(x);
  reduce_stats<<<256, 256, 0, stream>>>(0);
  bn_params<<<1, 64, 0, stream>>>(0, 64, 0, bn1g, bn1b);
  bn_params<<<1, 64, 0, stream>>>(128, 192, 128, scg, scb);

  ode_kernel<false><<<16384, 256, 0, stream>>>(0, o1w, t1w, t1b, 0.3, nullptr);

  conv2_kernel<<<1024, 256, 0, stream>>>();
  reduce_stats<<<128, 256, 0, stream>>>(256);
  bn_params<<<1, 64, 0, stream>>>(256, 320, 256, bn2g, bn2b);

  ode_kernel<true><<<16384, 256, 0, stream>>>(256, o2w, t2w, t2b, 0.5, (float*)d_out);
}